// Round 1
// 91.006 us; speedup vs baseline: 1.0247x; 1.0247x over previous
//
#include <hip/hip_runtime.h>
#include <math.h>

// BispectrumCalculator:
//   y = fft(target)  [B,T,N] complex
//   Bx[k,l] = y[k] * conj(y[l]) * y[(l-k) mod N]
//   source = stack([Bx.re, Bx.im], ch).mean(T)  -> [B, 2, N, N]
//   outputs: (source, target)  -> d_out = source flat (16,777,216) ++ target flat (65,536)
//
// Window model (r2-r6): harness re-poison of d_ws (269 MB, ~46us) + d_out
// (67 MB, ~11us) is inside the measured window; controllable slice (dft +
// bispec) ~37us of the 93us window.
//
// r6: bispec restructured from (C=2 strided cols, K=8 rows, 24 ds_read/t)
// to (C=4 ADJACENT cols, K=4 rows, 15 ds_read/t): the 7-wide sliding
// window is shared across all 16 (kk,c) outputs. Adjacent columns make
// lane stride 32 B (16-way bank alias), fixed by a full bit-permutation
// swizzle within each 64-entry tile:
//     sw(idx) = (idx&~63) | ((idx&3)<<4) | ((idx>>2)&15)
// which moves the intra-thread offset bits (idx&3) out of the bank field
// and pulls 4 lane bits in -> all window/b reads hit 16 bank-pairs x 4
// lanes (the wave64-b64 floor). av reads stay wave-uniform broadcasts.
// The doubled-ring (+512) and per-t (+1024) offsets are multiples of 64,
// so they commute with sw(): swizzled addresses are computed once and
// reused across t via immediate ds offsets. Stores: 8x dwordx4 (was 32
// dwords).

#define NN 512
#define TT 4
#define BB 32

// bijective within each 64-entry (512 B) float2 tile
__device__ __forceinline__ int sw_idx(int idx) {
    return (idx & ~63) | ((idx & 3) << 4) | ((idx >> 2) & 15);
}

// ---------------------------------------------------------------------------
// Kernel A: DFT-512 per (b,t), n-split for occupancy (unchanged from r4).
// Grid = 512 blocks x 256 threads; tid = nh*128+kl, k = kq*128+kl.
// Rotor seeds via exact mod-512 phase reduction; nh=1 partials via LDS.
// kq==0 also copies the target row to the output tail (fused passthrough).
// ---------------------------------------------------------------------------
__global__ __launch_bounds__(256) void dft_kernel(const float* __restrict__ x,
                                                  float2* __restrict__ y,
                                                  float* __restrict__ tail) {
    __shared__ float2 part[128];

    int bt = blockIdx.x >> 2;
    int kq = blockIdx.x & 3;
    int kl = threadIdx.x & 127;
    int nh = threadIdx.x >> 7;
    int k  = (kq << 7) | kl;
    const float* xp = x + (size_t)bt * NN;

    if (kq == 0 && nh == 0) {
        ((float4*)(tail + (size_t)bt * NN))[kl] = ((const float4*)xp)[kl];
    }

    int n0 = nh << 8;  // 0 or 256
    const float twopi_n = -2.0f * (float)M_PI / (float)NN;

    float2 w0, w1, w2, w3;
    float s4, c4;
    {
        int m0 = (k * (n0 + 0)) & (NN - 1);
        int m1 = (k * (n0 + 1)) & (NN - 1);
        int m2 = (k * (n0 + 2)) & (NN - 1);
        int m3 = (k * (n0 + 3)) & (NN - 1);
        int m4 = (k * 4) & (NN - 1);
        sincosf(twopi_n * (float)m0, &w0.y, &w0.x);
        sincosf(twopi_n * (float)m1, &w1.y, &w1.x);
        sincosf(twopi_n * (float)m2, &w2.y, &w2.x);
        sincosf(twopi_n * (float)m3, &w3.y, &w3.x);
        sincosf(twopi_n * (float)m4, &s4, &c4);
    }

    float2 a0 = make_float2(0.f, 0.f), a1 = a0, a2 = a0, a3 = a0;

    #pragma unroll 4
    for (int n = n0; n < n0 + 256; n += 4) {
        float x0 = xp[n];
        float x1 = xp[n + 1];
        float x2 = xp[n + 2];
        float x3 = xp[n + 3];
        a0.x += x0 * w0.x; a0.y += x0 * w0.y;
        a1.x += x1 * w1.x; a1.y += x1 * w1.y;
        a2.x += x2 * w2.x; a2.y += x2 * w2.y;
        a3.x += x3 * w3.x; a3.y += x3 * w3.y;
        float t;
        t = w0.x * c4 - w0.y * s4; w0.y = w0.x * s4 + w0.y * c4; w0.x = t;
        t = w1.x * c4 - w1.y * s4; w1.y = w1.x * s4 + w1.y * c4; w1.x = t;
        t = w2.x * c4 - w2.y * s4; w2.y = w2.x * s4 + w2.y * c4; w2.x = t;
        t = w3.x * c4 - w3.y * s4; w3.y = w3.x * s4 + w3.y * c4; w3.x = t;
    }

    float re = (a0.x + a1.x) + (a2.x + a3.x);
    float im = (a0.y + a1.y) + (a2.y + a3.y);

    if (nh == 1) {
        part[kl] = make_float2(re, im);
    }
    __syncthreads();
    if (nh == 0) {
        float2 p = part[kl];
        y[(size_t)bt * NN + k] = make_float2(re + p.x, im + p.y);
    }
}

// ---------------------------------------------------------------------------
// Kernel B: bispectrum. Grid = B * 64 blocks x 256 threads.
// Block = one b, 8 consecutive k-rows (2 kgroups x 4 rows), all 512 cols.
// Thread = 4 rows x 4 ADJACENT cols; shared 7-wide c-window per t.
// Swizzled doubled LDS ring (see header comment) keeps every read at the
// wave64 bank floor. 60 ds_read_b64/thread (was 104), 8 dwordx4 stores
// (was 32 dwords).
// ---------------------------------------------------------------------------
__global__ __launch_bounds__(256) void bispec_kernel(const float2* __restrict__ y,
                                                     float* __restrict__ out) {
    __shared__ float2 ring[TT * 2 * NN];  // 32 KiB, doubled + swizzled

    int b   = blockIdx.x >> 6;
    int kb  = blockIdx.x & 63;   // 8-row group
    int tid = threadIdx.x;

    // stage y[b] -> swizzled doubled ring (global: [t][256] float4)
    const float4* src = (const float4*)(y + (size_t)b * TT * NN);
    #pragma unroll
    for (int i = 0; i < 4; ++i) {
        int g = tid + 256 * i;          // [0,1024)
        int t = g >> 8;
        int j = g & 255;                // float4 index within t-row
        float4 v = src[g];
        int s0 = sw_idx((t << 10) + 2 * j);   // i0 even -> sw(i0+1)=sw(i0)+16
        ring[s0]       = make_float2(v.x, v.y);
        ring[s0 + 16]  = make_float2(v.z, v.w);
        ring[s0 + 512] = make_float2(v.x, v.y);   // doubled copy: sw(idx+512)=sw(idx)+512
        ring[s0 + 528] = make_float2(v.z, v.w);
    }
    __syncthreads();

    int kg    = tid >> 7;            // wave-uniform (waves 0,1 -> 0; 2,3 -> 1)
    int ll    = tid & 127;
    int l0    = ll << 2;             // 4 adjacent columns l0..l0+3
    int kbase = (kb << 3) | (kg << 2);  // this thread's 4 rows

    // swizzled t=0 indices, reused across t via +t*1024 (commutes with sw)
    int w0 = (l0 - kbase - 3) & (NN - 1);  // window start; w0+6 < 1024 in doubled ring
    int swj[7];
    #pragma unroll
    for (int j = 0; j < 7; ++j) swj[j] = sw_idx(w0 + j);
    int sa = sw_idx(kbase);   // kbase%4==0 -> av[kk] at sa + 16*kk (kk<4)
    int sb = sw_idx(l0);      // l0%4==0   -> bb[c]  at sb + 16*c

    float r[4][4], q[4][4];
    #pragma unroll
    for (int kk = 0; kk < 4; ++kk)
        #pragma unroll
        for (int c = 0; c < 4; ++c) { r[kk][c] = 0.f; q[kk][c] = 0.f; }

    #pragma unroll
    for (int t = 0; t < TT; ++t) {
        const float2* rt = ring + (t << 10);
        float2 cw[7], av[4], bb[4];
        #pragma unroll
        for (int j = 0; j < 7; ++j) cw[j] = rt[swj[j]];        // lane-spread, conflict-free
        #pragma unroll
        for (int kk = 0; kk < 4; ++kk) av[kk] = rt[sa + (kk << 4)];  // wave-uniform broadcast
        #pragma unroll
        for (int c = 0; c < 4; ++c)  bb[c]  = rt[sb + (c << 4)];     // lane-spread

        #pragma unroll
        for (int kk = 0; kk < 4; ++kk) {
            float2 a = av[kk];
            #pragma unroll
            for (int c = 0; c < 4; ++c) {
                float2 cv = cw[3 - kk + c];   // = y_t[(l0+c - kbase-kk) mod 512]
                float2 bv = bb[c];            // = y_t[l0+c]
                float ur = a.x * cv.x - a.y * cv.y;
                float ui = a.x * cv.y + a.y * cv.x;
                r[kk][c] += ur * bv.x + ui * bv.y;   // Re(a*cv*conj(bv))
                q[kk][c] += ui * bv.x - ur * bv.y;   // Im(a*cv*conj(bv))
            }
        }
    }

    float* outb = out + (size_t)b * 2 * NN * NN;
    #pragma unroll
    for (int kk = 0; kk < 4; ++kk) {
        size_t rk = (size_t)(kbase + kk) * NN + l0;
        float4 vr = make_float4(r[kk][0] * 0.25f, r[kk][1] * 0.25f,
                                r[kk][2] * 0.25f, r[kk][3] * 0.25f);
        float4 vq = make_float4(q[kk][0] * 0.25f, q[kk][1] * 0.25f,
                                q[kk][2] * 0.25f, q[kk][3] * 0.25f);
        *(float4*)(outb + rk)                    = vr;  // real ch
        *(float4*)(outb + (size_t)NN * NN + rk)  = vq;  // imag ch
    }
}

extern "C" void kernel_launch(void* const* d_in, const int* in_sizes, int n_in,
                              void* d_out, int out_size, void* d_ws, size_t ws_size,
                              hipStream_t stream) {
    const float* target = (const float*)d_in[0];
    float* out = (float*)d_out;
    // workspace: y spectrum, B*T*N complex64 = 512 KiB
    float2* y = (float2*)d_ws;
    float* tail = out + (size_t)BB * 2 * NN * NN;  // target passthrough

    dft_kernel<<<BB * TT * 4, 256, 0, stream>>>(target, y, tail);
    bispec_kernel<<<BB * 64, 256, 0, stream>>>(y, out);
}

// Round 2
// 87.124 us; speedup vs baseline: 1.0704x; 1.0446x over previous
//
#include <hip/hip_runtime.h>
#include <math.h>

// BispectrumCalculator:
//   y = fft(target)  [B,T,N] complex
//   Bx[k,l] = y[k] * conj(y[l]) * y[(l-k) mod N]
//   source = stack([Bx.re, Bx.im], ch).mean(T)  -> [B, 2, N, N]
//   outputs: (source, target)  -> d_out = source flat (16,777,216) ++ target flat (65,536)
//
// Window model (r2-r7): harness re-poison of d_ws (257 MiB, ~46us) + d_out
// (64 MiB, ~11us) is inside the measured window; controllable slice (dft +
// bispec) ~34us of the 91us window.
//
// r7: dft exploits real-input Hermitian symmetry (y[N-k] = conj(y[k])):
// compute k in [0,256) only, mirror-store conj to 512-k, y[256] via the
// alternating sum folded into kq==0 blocks. Same grid geometry (512 blocks
// x 256 threads, 2 waves/SIMD), per-thread trip count 64 -> 32. bispec is
// byte-identical to r6 (C=4 adjacent cols / K=4 rows / swizzled ring) --
// r6 showed it is near its ~11-13us store floor.

#define NN 512
#define TT 4
#define BB 32

// bijective within each 64-entry (512 B) float2 tile
__device__ __forceinline__ int sw_idx(int idx) {
    return (idx & ~63) | ((idx & 3) << 4) | ((idx >> 2) & 15);
}

// ---------------------------------------------------------------------------
// Kernel A: Hermitian DFT-512 per (b,t).
// Grid = 128 bt x 4 kq = 512 blocks, 256 threads = 64 kl x 4 nh.
// k = kq*64 + kl in [0,256); each thread sums n in [nh*128, nh*128+128).
// Rotor seeds via exact mod-512 phase reduction; nh partials combined in
// LDS; nh==0 stores y[k] and conj to y[512-k]. kq==0 also computes y[256]
// (alternating sum, +1 FMA/n) and copies the target row to the output tail.
// ---------------------------------------------------------------------------
__global__ __launch_bounds__(256) void dft_kernel(const float* __restrict__ x,
                                                  float2* __restrict__ y,
                                                  float* __restrict__ tail) {
    __shared__ float2 part[192];      // nh = 1..3 partials, [nh-1][kl]
    __shared__ float  salt[4];        // alternating-sum partials per nh

    int bt = blockIdx.x >> 2;
    int kq = blockIdx.x & 3;
    int kl = threadIdx.x & 63;
    int nh = threadIdx.x >> 6;
    int k  = (kq << 6) | kl;          // [0,256)
    const float* xp = x + (size_t)bt * NN;

    if (kq == 0 && nh == 0) {
        // target passthrough: 64 lanes x 2 float4 = 2 KiB row
        ((float4*)(tail + (size_t)bt * NN))[kl]      = ((const float4*)xp)[kl];
        ((float4*)(tail + (size_t)bt * NN))[kl + 64] = ((const float4*)xp)[kl + 64];
    }

    int n0 = nh << 7;  // 0,128,256,384
    const float twopi_n = -2.0f * (float)M_PI / (float)NN;

    float2 w0, w1, w2, w3;
    float s4, c4;
    {
        int m0 = (k * (n0 + 0)) & (NN - 1);
        int m1 = (k * (n0 + 1)) & (NN - 1);
        int m2 = (k * (n0 + 2)) & (NN - 1);
        int m3 = (k * (n0 + 3)) & (NN - 1);
        int m4 = (k * 4) & (NN - 1);
        sincosf(twopi_n * (float)m0, &w0.y, &w0.x);
        sincosf(twopi_n * (float)m1, &w1.y, &w1.x);
        sincosf(twopi_n * (float)m2, &w2.y, &w2.x);
        sincosf(twopi_n * (float)m3, &w3.y, &w3.x);
        sincosf(twopi_n * (float)m4, &s4, &c4);
    }

    float2 a0 = make_float2(0.f, 0.f), a1 = a0, a2 = a0, a3 = a0;
    float sa = 0.f;  // alternating sum partial (kq==0 only)

    if (kq == 0) {
        #pragma unroll 4
        for (int n = n0; n < n0 + 128; n += 4) {
            float x0 = xp[n];
            float x1 = xp[n + 1];
            float x2 = xp[n + 2];
            float x3 = xp[n + 3];
            sa += (x0 - x1) + (x2 - x3);   // n0 even -> signs +,-,+,-
            a0.x += x0 * w0.x; a0.y += x0 * w0.y;
            a1.x += x1 * w1.x; a1.y += x1 * w1.y;
            a2.x += x2 * w2.x; a2.y += x2 * w2.y;
            a3.x += x3 * w3.x; a3.y += x3 * w3.y;
            float t;
            t = w0.x * c4 - w0.y * s4; w0.y = w0.x * s4 + w0.y * c4; w0.x = t;
            t = w1.x * c4 - w1.y * s4; w1.y = w1.x * s4 + w1.y * c4; w1.x = t;
            t = w2.x * c4 - w2.y * s4; w2.y = w2.x * s4 + w2.y * c4; w2.x = t;
            t = w3.x * c4 - w3.y * s4; w3.y = w3.x * s4 + w3.y * c4; w3.x = t;
        }
    } else {
        #pragma unroll 4
        for (int n = n0; n < n0 + 128; n += 4) {
            float x0 = xp[n];
            float x1 = xp[n + 1];
            float x2 = xp[n + 2];
            float x3 = xp[n + 3];
            a0.x += x0 * w0.x; a0.y += x0 * w0.y;
            a1.x += x1 * w1.x; a1.y += x1 * w1.y;
            a2.x += x2 * w2.x; a2.y += x2 * w2.y;
            a3.x += x3 * w3.x; a3.y += x3 * w3.y;
            float t;
            t = w0.x * c4 - w0.y * s4; w0.y = w0.x * s4 + w0.y * c4; w0.x = t;
            t = w1.x * c4 - w1.y * s4; w1.y = w1.x * s4 + w1.y * c4; w1.x = t;
            t = w2.x * c4 - w2.y * s4; w2.y = w2.x * s4 + w2.y * c4; w2.x = t;
            t = w3.x * c4 - w3.y * s4; w3.y = w3.x * s4 + w3.y * c4; w3.x = t;
        }
    }

    float re = (a0.x + a1.x) + (a2.x + a3.x);
    float im = (a0.y + a1.y) + (a2.y + a3.y);

    if (nh) {
        part[((nh - 1) << 6) + kl] = make_float2(re, im);
    }
    if (kq == 0 && kl == 0) {
        salt[nh] = sa;
    }
    __syncthreads();

    if (nh == 0) {
        float2 p0 = part[kl];
        float2 p1 = part[64 + kl];
        float2 p2 = part[128 + kl];
        float rr = ((re + p0.x) + (p1.x + p2.x));
        float ii = ((im + p0.y) + (p1.y + p2.y));
        float2* yb = y + (size_t)bt * NN;
        yb[k] = make_float2(rr, ii);
        if (k != 0) {
            yb[NN - k] = make_float2(rr, -ii);   // Hermitian mirror
        }
        if (kq == 0 && kl == 0) {
            yb[NN / 2] = make_float2((salt[0] + salt[1]) + (salt[2] + salt[3]), 0.f);
        }
    }
}

// ---------------------------------------------------------------------------
// Kernel B: bispectrum (byte-identical to r6). Grid = B * 64 blocks x 256
// threads. Block = one b, 8 consecutive k-rows (2 kgroups x 4 rows), all
// 512 cols. Thread = 4 rows x 4 ADJACENT cols; shared 7-wide c-window per
// t. Swizzled doubled LDS ring keeps every read at the wave64 bank floor:
//     sw(idx) = (idx&~63) | ((idx&3)<<4) | ((idx>>2)&15)
// 60 ds_read_b64/thread, 8 dwordx4 stores.
// ---------------------------------------------------------------------------
__global__ __launch_bounds__(256) void bispec_kernel(const float2* __restrict__ y,
                                                     float* __restrict__ out) {
    __shared__ float2 ring[TT * 2 * NN];  // 32 KiB, doubled + swizzled

    int b   = blockIdx.x >> 6;
    int kb  = blockIdx.x & 63;   // 8-row group
    int tid = threadIdx.x;

    // stage y[b] -> swizzled doubled ring (global: [t][256] float4)
    const float4* src = (const float4*)(y + (size_t)b * TT * NN);
    #pragma unroll
    for (int i = 0; i < 4; ++i) {
        int g = tid + 256 * i;          // [0,1024)
        int t = g >> 8;
        int j = g & 255;                // float4 index within t-row
        float4 v = src[g];
        int s0 = sw_idx((t << 10) + 2 * j);   // i0 even -> sw(i0+1)=sw(i0)+16
        ring[s0]       = make_float2(v.x, v.y);
        ring[s0 + 16]  = make_float2(v.z, v.w);
        ring[s0 + 512] = make_float2(v.x, v.y);   // doubled copy: sw(idx+512)=sw(idx)+512
        ring[s0 + 528] = make_float2(v.z, v.w);
    }
    __syncthreads();

    int kg    = tid >> 7;            // wave-uniform (waves 0,1 -> 0; 2,3 -> 1)
    int ll    = tid & 127;
    int l0    = ll << 2;             // 4 adjacent columns l0..l0+3
    int kbase = (kb << 3) | (kg << 2);  // this thread's 4 rows

    // swizzled t=0 indices, reused across t via +t*1024 (commutes with sw)
    int w0 = (l0 - kbase - 3) & (NN - 1);  // window start; w0+6 < 1024 in doubled ring
    int swj[7];
    #pragma unroll
    for (int j = 0; j < 7; ++j) swj[j] = sw_idx(w0 + j);
    int sa = sw_idx(kbase);   // kbase%4==0 -> av[kk] at sa + 16*kk (kk<4)
    int sb = sw_idx(l0);      // l0%4==0   -> bb[c]  at sb + 16*c

    float r[4][4], q[4][4];
    #pragma unroll
    for (int kk = 0; kk < 4; ++kk)
        #pragma unroll
        for (int c = 0; c < 4; ++c) { r[kk][c] = 0.f; q[kk][c] = 0.f; }

    #pragma unroll
    for (int t = 0; t < TT; ++t) {
        const float2* rt = ring + (t << 10);
        float2 cw[7], av[4], bb[4];
        #pragma unroll
        for (int j = 0; j < 7; ++j) cw[j] = rt[swj[j]];        // lane-spread, conflict-free
        #pragma unroll
        for (int kk = 0; kk < 4; ++kk) av[kk] = rt[sa + (kk << 4)];  // wave-uniform broadcast
        #pragma unroll
        for (int c = 0; c < 4; ++c)  bb[c]  = rt[sb + (c << 4)];     // lane-spread

        #pragma unroll
        for (int kk = 0; kk < 4; ++kk) {
            float2 a = av[kk];
            #pragma unroll
            for (int c = 0; c < 4; ++c) {
                float2 cv = cw[3 - kk + c];   // = y_t[(l0+c - kbase-kk) mod 512]
                float2 bv = bb[c];            // = y_t[l0+c]
                float ur = a.x * cv.x - a.y * cv.y;
                float ui = a.x * cv.y + a.y * cv.x;
                r[kk][c] += ur * bv.x + ui * bv.y;   // Re(a*cv*conj(bv))
                q[kk][c] += ui * bv.x - ur * bv.y;   // Im(a*cv*conj(bv))
            }
        }
    }

    float* outb = out + (size_t)b * 2 * NN * NN;
    #pragma unroll
    for (int kk = 0; kk < 4; ++kk) {
        size_t rk = (size_t)(kbase + kk) * NN + l0;
        float4 vr = make_float4(r[kk][0] * 0.25f, r[kk][1] * 0.25f,
                                r[kk][2] * 0.25f, r[kk][3] * 0.25f);
        float4 vq = make_float4(q[kk][0] * 0.25f, q[kk][1] * 0.25f,
                                q[kk][2] * 0.25f, q[kk][3] * 0.25f);
        *(float4*)(outb + rk)                    = vr;  // real ch
        *(float4*)(outb + (size_t)NN * NN + rk)  = vq;  // imag ch
    }
}

extern "C" void kernel_launch(void* const* d_in, const int* in_sizes, int n_in,
                              void* d_out, int out_size, void* d_ws, size_t ws_size,
                              hipStream_t stream) {
    const float* target = (const float*)d_in[0];
    float* out = (float*)d_out;
    // workspace: y spectrum, B*T*N complex64 = 512 KiB
    float2* y = (float2*)d_ws;
    float* tail = out + (size_t)BB * 2 * NN * NN;  // target passthrough

    dft_kernel<<<BB * TT * 4, 256, 0, stream>>>(target, y, tail);
    bispec_kernel<<<BB * 64, 256, 0, stream>>>(y, out);
}